// Round 3
// baseline (320.795 us; speedup 1.0000x reference)
//
#include <hip/hip_runtime.h>

#define NB 16
#define NE 4
#define NC 4
#define NPIX (512 * 1024)

constexpr int THREADS = 256;
constexpr int BPB     = 128;                      // blocks per batch -> 2048 blocks
constexpr int UNITS   = NPIX / 4;                 // 131072 float4 units per batch
constexpr int ITERS   = UNITS / (BPB * THREADS);  // 4
#define WS_STRIDE 36
// ws[(b*BPB + bx)*36 + t]; t: [0..15]=sum[c*4+e], [16..31]=sumsq, [32..35]=count[c]

typedef float f32x4 __attribute__((ext_vector_type(4)));
typedef int   i32x4 __attribute__((ext_vector_type(4)));

__global__ __launch_bounds__(THREADS, 8) void accum_kernel(
    const float* __restrict__ pred,
    const float* __restrict__ mask,
    const int*   __restrict__ inst,
    float* __restrict__ ws)
{
    const int b   = blockIdx.y;
    const int bx  = blockIdx.x;
    const int tid = threadIdx.x;

    float s[NC][NE] = {};
    float q[NC][NE] = {};
    float n[NC]     = {};

    const f32x4* pm  = reinterpret_cast<const f32x4*>(mask + (size_t)b * NPIX);
    const i32x4* pi  = reinterpret_cast<const i32x4*>(inst + (size_t)b * NPIX);
    const f32x4* pp0 = reinterpret_cast<const f32x4*>(pred + ((size_t)b * NE + 0) * NPIX);
    const f32x4* pp1 = reinterpret_cast<const f32x4*>(pred + ((size_t)b * NE + 1) * NPIX);
    const f32x4* pp2 = reinterpret_cast<const f32x4*>(pred + ((size_t)b * NE + 2) * NPIX);
    const f32x4* pp3 = reinterpret_cast<const f32x4*>(pred + ((size_t)b * NE + 3) * NPIX);

    const int base = bx * (THREADS * ITERS) + tid;

    #pragma unroll
    for (int k = 0; k < ITERS; ++k) {
        const int u = base + k * THREADS;
        // nontemporal: stream-once data, don't allocate/evict caches
        const f32x4 m4 = __builtin_nontemporal_load(pm + u);
        const i32x4 i4 = __builtin_nontemporal_load(pi + u);
        f32x4 p4[NE];
        p4[0] = __builtin_nontemporal_load(pp0 + u);
        p4[1] = __builtin_nontemporal_load(pp1 + u);
        p4[2] = __builtin_nontemporal_load(pp2 + u);
        p4[3] = __builtin_nontemporal_load(pp3 + u);

        #pragma unroll
        for (int j = 0; j < 4; ++j) {
            const float mm  = m4[j];
            const int   lab = i4[j];
            float v[NE], sq[NE];
            #pragma unroll
            for (int e = 0; e < NE; ++e) {
                const float x = mm * p4[e][j];
                v[e]  = x;
                sq[e] = x * x;
            }
            #pragma unroll
            for (int c = 0; c < NC; ++c) {
                const float ind = (lab == c + 1) ? 1.0f : 0.0f;
                n[c] += ind;
                #pragma unroll
                for (int e = 0; e < NE; ++e) {
                    s[c][e] = fmaf(ind, v[e],  s[c][e]);
                    q[c][e] = fmaf(ind, sq[e], q[c][e]);
                }
            }
        }
    }

    // cheap tail: 2-step quad butterfly, then one LDS pass, per-block slot (no atomics)
    #pragma unroll
    for (int c = 0; c < NC; ++c) {
        #pragma unroll
        for (int e = 0; e < NE; ++e) {
            s[c][e] += __shfl_xor(s[c][e], 1); s[c][e] += __shfl_xor(s[c][e], 2);
            q[c][e] += __shfl_xor(q[c][e], 1); q[c][e] += __shfl_xor(q[c][e], 2);
        }
        n[c] += __shfl_xor(n[c], 1); n[c] += __shfl_xor(n[c], 2);
    }

    __shared__ float red[64][WS_STRIDE];
    const int lane = tid & 63, wave = tid >> 6;
    if ((lane & 3) == 0) {
        float* dst = red[wave * 16 + (lane >> 2)];
        #pragma unroll
        for (int c = 0; c < NC; ++c) {
            #pragma unroll
            for (int e = 0; e < NE; ++e) {
                dst[c * 4 + e]      = s[c][e];
                dst[16 + c * 4 + e] = q[c][e];
            }
            dst[32 + c] = n[c];
        }
    }
    __syncthreads();

    if (tid < WS_STRIDE) {
        float tot = 0.0f;
        #pragma unroll
        for (int p2 = 0; p2 < 64; ++p2) tot += red[p2][tid];
        ws[((size_t)(b * BPB + bx)) * WS_STRIDE + tid] = tot;
    }
}

constexpr int FT = 640;
__global__ __launch_bounds__(FT) void finalize_kernel(
    const float* __restrict__ ws, float* __restrict__ out)
{
    __shared__ float fin[NB * WS_STRIDE];   // 576
    const int t = threadIdx.x;
    if (t < NB * WS_STRIDE) {
        const int b = t / WS_STRIDE, v = t % WS_STRIDE;
        float tot = 0.0f;
        #pragma unroll 8
        for (int blk = 0; blk < BPB; ++blk)
            tot += ws[((size_t)(b * BPB + blk)) * WS_STRIDE + v];
        fin[t] = tot;
    }
    __syncthreads();

    if (t < 64) {
        const int lane = t;
        const int b = lane >> 2;
        const int c = lane & 3;
        const float* wb = fin + b * WS_STRIDE;

        const float cnt = wb[32 + c];
        float mu[NE];
        float ssd = 0.0f;
        #pragma unroll
        for (int e = 0; e < NE; ++e) {
            const float sm = wb[c * 4 + e];
            const float qq = wb[16 + c * 4 + e];
            const float m  = sm / cnt;
            mu[e] = m;
            ssd += qq - cnt * m * m;
        }
        ssd = fmaxf(ssd, 0.0f);
        const float nrm = sqrtf(ssd);
        const float dv  = nrm - 0.5f;
        float var = (nrm > 0.5f) ? dv * dv : 0.0f;

        float dsum = 0.0f;
        const int qbase = lane & ~3;
        #pragma unroll
        for (int j = 0; j < NC; ++j) {
            float d2 = 0.0f;
            #pragma unroll
            for (int e = 0; e < NE; ++e) {
                const float mj = __shfl(mu[e], qbase + j);
                const float df = mu[e] - mj;
                d2 = fmaf(df, df, d2);
            }
            if (j != c) {
                const float dist = sqrtf(d2);
                const float r = fmaxf(3.0f - dist, 0.0f);
                dsum += r * r;
            }
        }

        #pragma unroll
        for (int off = 32; off; off >>= 1) {
            var  += __shfl_xor(var,  off);
            dsum += __shfl_xor(dsum, off);
        }
        if (lane == 0)
            out[0] = var / (float)(NB * NC) + dsum / (float)NB;
    }
}

extern "C" void kernel_launch(void* const* d_in, const int* in_sizes, int n_in,
                              void* d_out, int out_size, void* d_ws, size_t ws_size,
                              hipStream_t stream) {
    const float* pred = (const float*)d_in[0];
    const float* mask = (const float*)d_in[1];
    const int*   inst = (const int*)d_in[2];
    float* out = (float*)d_out;
    float* ws  = (float*)d_ws;

    dim3 grid(BPB, NB);
    accum_kernel<<<grid, THREADS, 0, stream>>>(pred, mask, inst, ws);
    finalize_kernel<<<1, FT, 0, stream>>>(ws, out);
}

// Round 4
// 240.252 us; speedup vs baseline: 1.3352x; 1.3352x over previous
//
#include <hip/hip_runtime.h>

#define NB 16
#define NE 4
#define NC 4
#define NPIX (512 * 1024)

constexpr int THREADS = 256;
constexpr int BPB     = 128;                      // blocks per batch -> 2048 blocks
constexpr int UNITS   = NPIX / 4;                 // 131072 float4 units per batch
constexpr int ITERS   = UNITS / (BPB * THREADS);  // 4
#define WS_STRIDE 36
// ws[(b*BPB + bx)*36 + t]; t: [0..15]=sum[c*4+e], [16..31]=sumsq, [32..35]=count[c]

typedef float f32x4 __attribute__((ext_vector_type(4)));
typedef int   i32x4 __attribute__((ext_vector_type(4)));

__global__ __launch_bounds__(THREADS) void accum_kernel(
    const float* __restrict__ pred,
    const float* __restrict__ mask,
    const int*   __restrict__ inst,
    float* __restrict__ ws)
{
    const int b   = blockIdx.y;
    const int bx  = blockIdx.x;
    const int tid = threadIdx.x;

    float s[NC][NE] = {};
    float q[NC][NE] = {};
    float n[NC]     = {};

    const f32x4* pm  = reinterpret_cast<const f32x4*>(mask + (size_t)b * NPIX);
    const i32x4* pi  = reinterpret_cast<const i32x4*>(inst + (size_t)b * NPIX);
    const f32x4* pp0 = reinterpret_cast<const f32x4*>(pred + ((size_t)b * NE + 0) * NPIX);
    const f32x4* pp1 = reinterpret_cast<const f32x4*>(pred + ((size_t)b * NE + 1) * NPIX);
    const f32x4* pp2 = reinterpret_cast<const f32x4*>(pred + ((size_t)b * NE + 2) * NPIX);
    const f32x4* pp3 = reinterpret_cast<const f32x4*>(pred + ((size_t)b * NE + 3) * NPIX);

    #pragma unroll
    for (int k = 0; k < ITERS; ++k) {
        // block-interleaved sweep: all resident blocks advance through ONE
        // contiguous window per (batch, stream) -> ~96 sequential DRAM fronts
        // instead of ~6000 private ones.
        const int u = k * (BPB * THREADS) + bx * THREADS + tid;

        const f32x4 m4 = pm[u];
        const i32x4 i4 = pi[u];
        f32x4 p4[NE];
        p4[0] = pp0[u]; p4[1] = pp1[u]; p4[2] = pp2[u]; p4[3] = pp3[u];

        #pragma unroll
        for (int j = 0; j < 4; ++j) {
            const float mm  = m4[j];
            const int   lab = i4[j];
            float v[NE], sq[NE];
            #pragma unroll
            for (int e = 0; e < NE; ++e) {
                const float x = mm * p4[e][j];
                v[e]  = x;
                sq[e] = x * x;
            }
            #pragma unroll
            for (int c = 0; c < NC; ++c) {
                const float ind = (lab == c + 1) ? 1.0f : 0.0f;
                n[c] += ind;
                #pragma unroll
                for (int e = 0; e < NE; ++e) {
                    s[c][e] = fmaf(ind, v[e],  s[c][e]);
                    q[c][e] = fmaf(ind, sq[e], q[c][e]);
                }
            }
        }
    }

    // cheap tail: 2-step quad butterfly, then one LDS pass, per-block slot (no atomics)
    #pragma unroll
    for (int c = 0; c < NC; ++c) {
        #pragma unroll
        for (int e = 0; e < NE; ++e) {
            s[c][e] += __shfl_xor(s[c][e], 1); s[c][e] += __shfl_xor(s[c][e], 2);
            q[c][e] += __shfl_xor(q[c][e], 1); q[c][e] += __shfl_xor(q[c][e], 2);
        }
        n[c] += __shfl_xor(n[c], 1); n[c] += __shfl_xor(n[c], 2);
    }

    __shared__ float red[64][WS_STRIDE];
    const int lane = tid & 63, wave = tid >> 6;
    if ((lane & 3) == 0) {
        float* dst = red[wave * 16 + (lane >> 2)];
        #pragma unroll
        for (int c = 0; c < NC; ++c) {
            #pragma unroll
            for (int e = 0; e < NE; ++e) {
                dst[c * 4 + e]      = s[c][e];
                dst[16 + c * 4 + e] = q[c][e];
            }
            dst[32 + c] = n[c];
        }
    }
    __syncthreads();

    if (tid < WS_STRIDE) {
        float tot = 0.0f;
        #pragma unroll
        for (int p2 = 0; p2 < 64; ++p2) tot += red[p2][tid];
        ws[((size_t)(b * BPB + bx)) * WS_STRIDE + tid] = tot;
    }
}

constexpr int FT = 640;
__global__ __launch_bounds__(FT) void finalize_kernel(
    const float* __restrict__ ws, float* __restrict__ out)
{
    __shared__ float fin[NB * WS_STRIDE];   // 576
    const int t = threadIdx.x;
    if (t < NB * WS_STRIDE) {
        const int b = t / WS_STRIDE, v = t % WS_STRIDE;
        float tot = 0.0f;
        #pragma unroll 8
        for (int blk = 0; blk < BPB; ++blk)
            tot += ws[((size_t)(b * BPB + blk)) * WS_STRIDE + v];
        fin[t] = tot;
    }
    __syncthreads();

    if (t < 64) {
        const int lane = t;
        const int b = lane >> 2;
        const int c = lane & 3;
        const float* wb = fin + b * WS_STRIDE;

        const float cnt = wb[32 + c];
        float mu[NE];
        float ssd = 0.0f;
        #pragma unroll
        for (int e = 0; e < NE; ++e) {
            const float sm = wb[c * 4 + e];
            const float qq = wb[16 + c * 4 + e];
            const float m  = sm / cnt;
            mu[e] = m;
            ssd += qq - cnt * m * m;
        }
        ssd = fmaxf(ssd, 0.0f);
        const float nrm = sqrtf(ssd);
        const float dv  = nrm - 0.5f;
        float var = (nrm > 0.5f) ? dv * dv : 0.0f;

        float dsum = 0.0f;
        const int qbase = lane & ~3;
        #pragma unroll
        for (int j = 0; j < NC; ++j) {
            float d2 = 0.0f;
            #pragma unroll
            for (int e = 0; e < NE; ++e) {
                const float mj = __shfl(mu[e], qbase + j);
                const float df = mu[e] - mj;
                d2 = fmaf(df, df, d2);
            }
            if (j != c) {
                const float dist = sqrtf(d2);
                const float r = fmaxf(3.0f - dist, 0.0f);
                dsum += r * r;
            }
        }

        #pragma unroll
        for (int off = 32; off; off >>= 1) {
            var  += __shfl_xor(var,  off);
            dsum += __shfl_xor(dsum, off);
        }
        if (lane == 0)
            out[0] = var / (float)(NB * NC) + dsum / (float)NB;
    }
}

extern "C" void kernel_launch(void* const* d_in, const int* in_sizes, int n_in,
                              void* d_out, int out_size, void* d_ws, size_t ws_size,
                              hipStream_t stream) {
    const float* pred = (const float*)d_in[0];
    const float* mask = (const float*)d_in[1];
    const int*   inst = (const int*)d_in[2];
    float* out = (float*)d_out;
    float* ws  = (float*)d_ws;

    dim3 grid(BPB, NB);
    accum_kernel<<<grid, THREADS, 0, stream>>>(pred, mask, inst, ws);
    finalize_kernel<<<1, FT, 0, stream>>>(ws, out);
}